// Round 1
// 631.820 us; speedup vs baseline: 1.0345x; 1.0345x over previous
//
#include <hip/hip_runtime.h>
#include <cstddef>
#include <cstdint>

// Problem constants (from reference): B=4, N=512, F_IN=64, F_OUT=128
#define BB   4
#define NN   512
#define FIN  64
#define FOUT 128
#define PARTS 4   // i-range split in k_edges (for occupancy); partial nn sums combined in k_final
#define JT    4   // j-columns per k_edges block (4 groups of 32 lanes)
#define CCH  16                    // i-rows staged per LDS chunk in k_edges
#define NCH  ((NN / PARTS) / CCH)  // 8 chunks per block

typedef float f4 __attribute__((ext_vector_type(4)));

__device__ __forceinline__ float celu1(float x) {
  // jax.nn.celu with alpha=1: x>0 ? x : exp(x)-1
  return x > 0.0f ? x : expm1f(x);
}

// ---------------------------------------------------------------------------
// K1: pj[bn,f] = nodes[bn,:] . edge_W[f, 0:64]
//     pip[bn,f] = nodes[bn,:] . edge_W[f, 64:128] + edge_b[f]
// One block per (b,n) row, 128 threads (one per f).
// ---------------------------------------------------------------------------
__global__ __launch_bounds__(FOUT) void k_proj(
    const float* __restrict__ nodes, const float* __restrict__ eW,
    const float* __restrict__ eb, float* __restrict__ pj,
    float* __restrict__ pip) {
  const int bn = blockIdx.x;
  const int f  = threadIdx.x;
  __shared__ __align__(16) float x[FIN];
  if (f < FIN) x[f] = nodes[bn * FIN + f];
  __syncthreads();
  const float* w = eW + f * (2 * FIN);
  float aj = 0.f, ai = 0.f;
#pragma unroll
  for (int k = 0; k < FIN; k += 4) {
    f4 xv = *(const f4*)(x + k);
    f4 wj = *(const f4*)(w + k);
    f4 wi = *(const f4*)(w + FIN + k);
    aj += wj.x * xv.x + wj.y * xv.y + wj.z * xv.z + wj.w * xv.w;
    ai += wi.x * xv.x + wi.y * xv.y + wi.z * xv.z + wi.w * xv.w;
  }
  pj[bn * FOUT + f]  = aj;
  pip[bn * FOUT + f] = ai + eb[f];
}

// ---------------------------------------------------------------------------
// K2: edges[b,i,j,f] = (pj[b,j,f] + pip[b,i,f]) * sk[b,i,j]   (512 MB write)
// Also accumulates nn_part[part,b,j,f] = sum over this block's i-range.
//
// Store-queue decoupling: loads and stores share vmcnt and decrement IN ORDER,
// so any load consumed inside the store loop forces a wait that drains all
// older nontemporal stores (observed ~1-2 TB/s effective). Fix: the inner loop
// touches ONLY LDS (lgkmcnt) + stores (never waited). pip is staged per-chunk
// into a double-buffered LDS tile (one vmcnt wait per 16 iterations, with a
// full chunk of compute as slack); the block's skeleton slab (128 i x 4 j) is
// staged once at block start.
// ---------------------------------------------------------------------------
__global__ __launch_bounds__(128) void k_edges(
    const float* __restrict__ pj, const float* __restrict__ pip,
    const float* __restrict__ sk, float* __restrict__ edges,
    float* __restrict__ nn_part) {
  const int xb   = blockIdx.x;
  const int part = xb & (PARTS - 1);          // i-quarter
  const int jt   = (xb >> 2) & (NN / JT - 1); // j-tile
  const int b    = xb >> 9;                   // / (PARTS * N/JT) = /512

  const int tid = threadIdx.x;
  const int g   = tid >> 5;   // group -> j offset
  const int t   = tid & 31;   // lane -> f/4
  const int j   = jt * JT + g;
  const int fo  = t * 4;
  const int i0  = part * (NN / PARTS);

  __shared__ __align__(16) float lpip[2][CCH][FOUT];   // 16 KB double buffer
  __shared__ __align__(16) float lsk[NN / PARTS][JT];  // 2 KB, whole i-range

  // One-time: stage this block's skeleton slab [128 i][4 j] into LDS.
  {
    const float* skb = sk + ((size_t)b * NN + i0) * NN + jt * JT;
#pragma unroll
    for (int r = 0; r < (NN / PARTS) * JT / 128; ++r) {  // 4 steps
      const int idx = tid + 128 * r;
      const int ii  = idx >> 2;
      const int gg  = idx & 3;
      lsk[ii][gg] = skb[(size_t)ii * NN + gg];
    }
  }

  const f4 pjv = *(const f4*)(pj + (b * NN + j) * FOUT + fo);

  const float* pipb = pip + ((size_t)b * NN + i0) * FOUT;  // this block's slab
  float* ep = edges + ((size_t)(b * NN + i0) * NN + j) * FOUT + fo;

  // Prologue: stage chunk 0 into LDS buffer 0 (global -> reg -> ds_write).
  {
    f4 r0 = *(const f4*)(pipb + 4 * tid);
    f4 r1 = *(const f4*)(pipb + 4 * tid + 512);
    f4 r2 = *(const f4*)(pipb + 4 * tid + 1024);
    f4 r3 = *(const f4*)(pipb + 4 * tid + 1536);
    float* ld = &lpip[0][0][0];
    *(f4*)(ld + 4 * tid)        = r0;
    *(f4*)(ld + 4 * tid + 512)  = r1;
    *(f4*)(ld + 4 * tid + 1024) = r2;
    *(f4*)(ld + 4 * tid + 1536) = r3;
  }
  __syncthreads();

  f4 acc = {0.f, 0.f, 0.f, 0.f};
  for (int ch = 0; ch < NCH; ++ch) {
    const int cb = ch & 1;

    // Issue next chunk's global loads BEFORE the store loop (their vmcnt wait
    // happens only at the ds_write below, a full chunk of compute later).
    f4 n0, n1, n2, n3;
    if (ch + 1 < NCH) {
      const float* pc = pipb + (size_t)(ch + 1) * CCH * FOUT;
      n0 = *(const f4*)(pc + 4 * tid);
      n1 = *(const f4*)(pc + 4 * tid + 512);
      n2 = *(const f4*)(pc + 4 * tid + 1024);
      n3 = *(const f4*)(pc + 4 * tid + 1536);
    }

    // Inner loop: LDS reads + nontemporal stores only. No vmcnt waits here,
    // so each wave keeps ~16 KB of stores in flight.
#pragma unroll
    for (int c = 0; c < CCH; ++c) {
      f4 piv  = *(const f4*)(&lpip[cb][c][fo]);
      float s = lsk[ch * CCH + c][g];
      f4 v    = (pjv + piv) * s;
      acc += v;
      __builtin_nontemporal_store(v, (f4*)ep);
      ep += (size_t)NN * FOUT;
    }

    if (ch + 1 < NCH) {
      float* ld = &lpip[cb ^ 1][0][0];
      *(f4*)(ld + 4 * tid)        = n0;
      *(f4*)(ld + 4 * tid + 512)  = n1;
      *(f4*)(ld + 4 * tid + 1024) = n2;
      *(f4*)(ld + 4 * tid + 1536) = n3;
    }
    __syncthreads();
  }

  *(f4*)(nn_part + ((size_t)(part * BB + b) * NN + j) * FOUT + fo) = acc;
}

// ---------------------------------------------------------------------------
// K3: out0[bn,f] = mlp(nodes[bn,:]) + (sum_part nn_part)[bn,:] . node_W[f,:] + node_b[f]
// One block per (b,n) row, 128 threads (one per f). Intermediates in LDS.
// ---------------------------------------------------------------------------
__global__ __launch_bounds__(FOUT) void k_final(
    const float* __restrict__ nodes, const float* __restrict__ nn_part,
    const float* __restrict__ nW, const float* __restrict__ nb,
    const float* __restrict__ W0, const float* __restrict__ b0,
    const float* __restrict__ W1, const float* __restrict__ b1,
    const float* __restrict__ W2, const float* __restrict__ b2,
    float* __restrict__ out0) {
  const int bn = blockIdx.x;
  const int f  = threadIdx.x;
  __shared__ __align__(16) float x[FIN];
  __shared__ __align__(16) float r[FOUT];
  __shared__ __align__(16) float hA[FOUT];
  __shared__ __align__(16) float hB[FOUT];

  if (f < FIN) x[f] = nodes[bn * FIN + f];
  {
    float s = 0.f;
#pragma unroll
    for (int p = 0; p < PARTS; ++p)
      s += nn_part[((size_t)(p * BB * NN) + bn) * FOUT + f];
    r[f] = s;
  }
  __syncthreads();

  // h0 = celu(W0 @ x + b0)
  float s0 = b0[f];
  {
    const float* w = W0 + f * FIN;
#pragma unroll
    for (int k = 0; k < FIN; k += 4) {
      f4 wv = *(const f4*)(w + k);
      f4 xv = *(const f4*)(x + k);
      s0 += wv.x * xv.x + wv.y * xv.y + wv.z * xv.z + wv.w * xv.w;
    }
  }
  hA[f] = celu1(s0);
  __syncthreads();

  // h1 = celu(W1 @ h0 + b1); node linear on r (independent of hA)
  float s1 = b1[f];
  {
    const float* w = W1 + f * FOUT;
#pragma unroll
    for (int k = 0; k < FOUT; k += 4) {
      f4 wv = *(const f4*)(w + k);
      f4 hv = *(const f4*)(hA + k);
      s1 += wv.x * hv.x + wv.y * hv.y + wv.z * hv.z + wv.w * hv.w;
    }
  }
  float nv = nb[f];
  {
    const float* w = nW + f * FOUT;
#pragma unroll
    for (int k = 0; k < FOUT; k += 4) {
      f4 wv = *(const f4*)(w + k);
      f4 rv = *(const f4*)(r + k);
      nv += wv.x * rv.x + wv.y * rv.y + wv.z * rv.z + wv.w * rv.w;
    }
  }
  hB[f] = celu1(s1);
  __syncthreads();

  // h2 = W2 @ h1 + b2 ; out = h2 + node_linear
  float s2 = b2[f];
  {
    const float* w = W2 + f * FOUT;
#pragma unroll
    for (int k = 0; k < FOUT; k += 4) {
      f4 wv = *(const f4*)(w + k);
      f4 hv = *(const f4*)(hB + k);
      s2 += wv.x * hv.x + wv.y * hv.y + wv.z * hv.z + wv.w * hv.w;
    }
  }
  out0[bn * FOUT + f] = s2 + nv;
}

// ---------------------------------------------------------------------------
extern "C" void kernel_launch(void* const* d_in, const int* in_sizes, int n_in,
                              void* d_out, int out_size, void* d_ws,
                              size_t ws_size, hipStream_t stream) {
  const float* nodes    = (const float*)d_in[0];
  const float* skeleton = (const float*)d_in[1];
  const float* edge_W   = (const float*)d_in[2];
  const float* edge_b   = (const float*)d_in[3];
  const float* node_W   = (const float*)d_in[4];
  const float* node_b   = (const float*)d_in[5];
  const float* mlp_W0   = (const float*)d_in[6];
  const float* mlp_b0   = (const float*)d_in[7];
  const float* mlp_W1   = (const float*)d_in[8];
  const float* mlp_b1   = (const float*)d_in[9];
  const float* mlp_W2   = (const float*)d_in[10];
  const float* mlp_b2   = (const float*)d_in[11];

  float* out0  = (float*)d_out;                 // [B,N,FOUT]
  float* edges = out0 + (size_t)BB * NN * FOUT; // [B,N,N,FOUT]

  float* ws      = (float*)d_ws;
  float* pj      = ws;                              // [B*N,FOUT]   1 MB
  float* pip     = ws + (size_t)BB * NN * FOUT;     // [B*N,FOUT]   1 MB
  float* nn_part = ws + (size_t)2 * BB * NN * FOUT; // [PARTS,B*N,FOUT] 4 MB

  k_proj<<<BB * NN, FOUT, 0, stream>>>(nodes, edge_W, edge_b, pj, pip);
  k_edges<<<BB * (NN / JT) * PARTS, 128, 0, stream>>>(pj, pip, skeleton, edges,
                                                      nn_part);
  k_final<<<BB * NN, FOUT, 0, stream>>>(nodes, nn_part, node_W, node_b, mlp_W0,
                                        mlp_b0, mlp_W1, mlp_b1, mlp_W2, mlp_b2,
                                        out0);
}